// Round 12
// baseline (125.596 us; speedup 1.0000x reference)
//
#include <hip/hip_runtime.h>
#include <hip/hip_fp8.h>
#include <math.h>

#define TAU 32.0f
#define LO_SCALE 2048.0f
#define INV_LO_SCALE (1.0f/2048.0f)

typedef _Float16 f16x8 __attribute__((ext_vector_type(8)));
typedef _Float16 f16x4 __attribute__((ext_vector_type(4)));
typedef __fp16   fp16v2 __attribute__((ext_vector_type(2)));   // cvt_pkrtz return type
typedef float    f32x2 __attribute__((ext_vector_type(2)));
typedef float    f32x16 __attribute__((ext_vector_type(16)));

#if defined(__has_builtin)
#if __has_builtin(__builtin_amdgcn_cvt_f32_fp8) && __has_builtin(__builtin_amdgcn_cvt_pk_fp8_f32)
#define HAVE_FP8_BUILTINS 1
#endif
#if __has_builtin(__builtin_amdgcn_cvt_pk_f32_fp8) && __has_builtin(__builtin_amdgcn_cvt_pkrtz)
#define HAVE_FP8_PK 1
#endif
#endif

static __device__ __forceinline__ unsigned char enc_e4m3(float x) {
#ifdef HAVE_FP8_BUILTINS
    int p = __builtin_amdgcn_cvt_pk_fp8_f32(x, x, 0, false);
    return (unsigned char)(p & 0xff);
#else
    __hip_fp8_e4m3 q(x);
    return (unsigned char)q.__x;
#endif
}

#ifdef HAVE_FP8_BUILTINS
#define DEC_E4M3(W, SEL) __builtin_amdgcn_cvt_f32_fp8((int)(W), (SEL))
#else
static __device__ __forceinline__ float dec_e4m3_sw(unsigned w, int sel) {
    __hip_fp8_e4m3 q; q.__x = (unsigned char)((w >> (8 * sel)) & 0xff);
    return (float)q;
}
#define DEC_E4M3(W, SEL) dec_e4m3_sw((W), (SEL))
#endif

// decode 8 fp8 (e4m3) bytes -> 8 f16 (packed path halves decode VALU)
static __device__ __forceinline__ f16x8 dec8(uint2 w) {
    f16x8 r;
#ifdef HAVE_FP8_PK
    f32x2 a = __builtin_amdgcn_cvt_pk_f32_fp8((int)w.x, false);
    f32x2 b = __builtin_amdgcn_cvt_pk_f32_fp8((int)w.x, true);
    f32x2 c = __builtin_amdgcn_cvt_pk_f32_fp8((int)w.y, false);
    f32x2 d = __builtin_amdgcn_cvt_pk_f32_fp8((int)w.y, true);
    fp16v2 h0 = __builtin_amdgcn_cvt_pkrtz(a[0], a[1]);
    fp16v2 h1 = __builtin_amdgcn_cvt_pkrtz(b[0], b[1]);
    fp16v2 h2 = __builtin_amdgcn_cvt_pkrtz(c[0], c[1]);
    fp16v2 h3 = __builtin_amdgcn_cvt_pkrtz(d[0], d[1]);
    r[0] = (_Float16)h0[0]; r[1] = (_Float16)h0[1];
    r[2] = (_Float16)h1[0]; r[3] = (_Float16)h1[1];
    r[4] = (_Float16)h2[0]; r[5] = (_Float16)h2[1];
    r[6] = (_Float16)h3[0]; r[7] = (_Float16)h3[1];
#else
    r[0] = (_Float16)DEC_E4M3(w.x, 0); r[1] = (_Float16)DEC_E4M3(w.x, 1);
    r[2] = (_Float16)DEC_E4M3(w.x, 2); r[3] = (_Float16)DEC_E4M3(w.x, 3);
    r[4] = (_Float16)DEC_E4M3(w.y, 0); r[5] = (_Float16)DEC_E4M3(w.y, 1);
    r[6] = (_Float16)DEC_E4M3(w.y, 2); r[7] = (_Float16)DEC_E4M3(w.y, 3);
#endif
    return r;
}

// ---------------------------------------------------------------------------
// Kernel 1 (v4, unchanged from R9 — dropped out of top-5): MW precompute in
// packed MFMA-fragment order; hi f16 + lo e4m3(x2048).
//   frag = (k/16)*6 + n/32 ; lane = ((k>>3)&1)*32 + (n&31), j = k&7
// ws: 192*768*2B + 192*768*1B = 442,368 B (fits proven 552,960).
// ---------------------------------------------------------------------------
__global__ __launch_bounds__(1024) void precompute_mw_packed(
    const float* __restrict__ Wt, const float* __restrict__ Wd,
    const float* __restrict__ dmem, _Float16* __restrict__ PBhi,
    unsigned char* __restrict__ PBlo)
{
    __shared__ float Ml[3 * 768];
    __shared__ float red[3][4][256];
    const int nt  = blockIdx.x;
    const int kc  = blockIdx.y;
    const int n0  = nt * 3;
    const int tid = threadIdx.x;
    const int q   = tid >> 8;
    const int kl  = tid & 255;
    const int k   = kc * 256 + kl;
    float v[3] = {0.f, 0.f, 0.f};
    if (n0 < 180) {
        const float* __restrict__ W = (n0 < 90) ? Wt : Wd;
        const int m0 = (n0 < 90) ? n0 : n0 - 90;
        for (int idx = tid; idx < 3 * 768; idx += 1024)
            Ml[idx] = dmem[m0 * 768 + idx];
        __syncthreads();
        const float* __restrict__ Wq  = W + (q * 192) * 768 + k;
        const float* __restrict__ mlb = Ml + q * 192;
        float a0 = 0.f, a1 = 0.f, a2 = 0.f;
        for (int e0 = 0; e0 < 192; e0 += 8) {
            float w[8];
            #pragma unroll
            for (int i = 0; i < 8; ++i)
                w[i] = Wq[(e0 + i) * 768];
            float4 m0a = *(const float4*)(mlb + e0);
            float4 m0b = *(const float4*)(mlb + e0 + 4);
            float4 m1a = *(const float4*)(mlb + 768 + e0);
            float4 m1b = *(const float4*)(mlb + 768 + e0 + 4);
            float4 m2a = *(const float4*)(mlb + 1536 + e0);
            float4 m2b = *(const float4*)(mlb + 1536 + e0 + 4);
            a0 = fmaf(m0a.x, w[0], a0); a0 = fmaf(m0a.y, w[1], a0);
            a0 = fmaf(m0a.z, w[2], a0); a0 = fmaf(m0a.w, w[3], a0);
            a0 = fmaf(m0b.x, w[4], a0); a0 = fmaf(m0b.y, w[5], a0);
            a0 = fmaf(m0b.z, w[6], a0); a0 = fmaf(m0b.w, w[7], a0);
            a1 = fmaf(m1a.x, w[0], a1); a1 = fmaf(m1a.y, w[1], a1);
            a1 = fmaf(m1a.z, w[2], a1); a1 = fmaf(m1a.w, w[3], a1);
            a1 = fmaf(m1b.x, w[4], a1); a1 = fmaf(m1b.y, w[5], a1);
            a1 = fmaf(m1b.z, w[6], a1); a1 = fmaf(m1b.w, w[7], a1);
            a2 = fmaf(m2a.x, w[0], a2); a2 = fmaf(m2a.y, w[1], a2);
            a2 = fmaf(m2a.z, w[2], a2); a2 = fmaf(m2a.w, w[3], a2);
            a2 = fmaf(m2b.x, w[4], a2); a2 = fmaf(m2b.y, w[5], a2);
            a2 = fmaf(m2b.z, w[6], a2); a2 = fmaf(m2b.w, w[7], a2);
        }
        red[0][q][kl] = a0;
        red[1][q][kl] = a1;
        red[2][q][kl] = a2;
        __syncthreads();
        if (q == 0) {
            #pragma unroll
            for (int i = 0; i < 3; ++i)
                v[i] = red[i][0][kl] + red[i][1][kl] + red[i][2][kl] + red[i][3][kl];
        }
    }
    if (q == 0) {
        const int t = k >> 5, ks = (k >> 4) & 1, h = (k >> 3) & 1, j = k & 7;
        const int fragc = (t * 2 + ks) * 6;
        #pragma unroll
        for (int i = 0; i < 3; ++i) {
            const int n = n0 + i;
            const int idx = (fragc + (n >> 5)) * 512 + (h * 32 + (n & 31)) * 8 + j;
            _Float16 hi = (_Float16)v[i];
            float lo = (v[i] - (float)hi) * LO_SCALE;
            PBhi[idx] = hi;
            PBlo[idx] = enc_e4m3(lo);
        }
    }
}

// ---------------------------------------------------------------------------
// Kernel 2 (v4): BM=32, 384 threads = 6 waves, wave wid owns col strip
// nt=wid (32 cols). Grid 1024 blocks -> 4 blocks/CU x 6 waves = 24 waves/CU
// (R9 was grid-capped at 8 waves/CU -> 18% occupancy, latency-bound).
// A LDS double-buffered (1 barrier/iter, 24 total vs 48); B 4-slot prefetch
// ring (load-to-use = 1 full iter); F prefetch distance 2. All slot/buffer
// indices compile-time (named regs + macro literals).
// ---------------------------------------------------------------------------
#define LOADB2(S, KL) do {                                   \
    Bh##S = *(const f16x8*)(pbh + (KL) * 3072);              \
    Bl##S = *(const uint2*)(pbl + (KL) * 3072);              \
} while (0)

#define CONV4(P, BUF) do {                                   \
    float _xs[4] = {(P).x, (P).y, (P).z, (P).w};             \
    f16x4 _h, _l;                                            \
    _Pragma("unroll")                                        \
    for (int _i = 0; _i < 4; ++_i) {                         \
        float _x = _xs[_i];                                  \
        _Float16 _hh = (_Float16)_x;                         \
        _h[_i] = _hh;                                        \
        _l[_i] = (_Float16)((_x - (float)_hh) * LO_SCALE);   \
        ps += _x * _x;                                       \
    }                                                        \
    *(f16x4*)((char*)AhL[BUF] + wb) = _h;                    \
    *(f16x4*)((char*)AlL[BUF] + wb) = _l;                    \
} while (0)

#define MBODY(BUF, KS, BH, BL) do {                          \
    const int _ao = (arow * 64 + (KS) * 32 + asel) ^ swzA;   \
    f16x8 _ah = *(const f16x8*)((const char*)AhL[BUF] + _ao);\
    f16x8 _al = *(const f16x8*)((const char*)AlL[BUF] + _ao);\
    f16x8 _bl = dec8(BL);                                    \
    acc1 = __builtin_amdgcn_mfma_f32_32x32x16_f16(_ah, BH, acc1, 0, 0, 0);  \
    acc2 = __builtin_amdgcn_mfma_f32_32x32x16_f16(_ah, _bl, acc2, 0, 0, 0); \
    acc2 = __builtin_amdgcn_mfma_f32_32x32x16_f16(_al, BH, acc2, 0, 0, 0);  \
} while (0)

__global__ __launch_bounds__(384, 6) void fused_memnet(
    const float* __restrict__ F, const _Float16* __restrict__ PBhi,
    const unsigned char* __restrict__ PBlo, float* __restrict__ out)
{
    __shared__ alignas(16) _Float16 AhL[2][32 * 32];  // 4 KB dbuf, swizzled
    __shared__ alignas(16) _Float16 AlL[2][32 * 32];  // 4 KB
    __shared__ float raw[32 * 196];                   // 25 KB epilogue
    __shared__ float ss[32];

    const int tid  = threadIdx.x;
    const int lane = tid & 63;
    const int wid  = tid / 64;        // 0..5 = col strip (nt)
    const int row0 = blockIdx.x * 32;

    // A staging ids (threads < 256 only)
    const int srow = (tid >> 3) & 31;
    const int sc4  = tid & 7;
    const float* __restrict__ Fp = F + (row0 + srow) * 768 + sc4 * 4;
    const int wb = (srow * 64 + sc4 * 8) ^ ((srow & 7) << 4);

    // packed-B per-lane bases: frag(kl, wid) at (kl*6+wid)*512 elems
    const _Float16*      __restrict__ pbh = PBhi + wid * 512 + lane * 8;
    const unsigned char* __restrict__ pbl = PBlo + wid * 512 + lane * 8;

    // A fragment read addressing
    const int arow = lane & 31;
    const int swzA = (arow & 7) << 4;
    const int asel = (lane >> 5) * 16;

    f32x16 acc1, acc2;
    #pragma unroll
    for (int r = 0; r < 16; ++r) { acc1[r] = 0.f; acc2[r] = 0.f; }

    float ps = 0.f;
    float4 p00, ppA, ppB;
    f16x8 Bh0, Bh1, Bh2, Bh3;
    uint2 Bl0, Bl1, Bl2, Bl3;

    // prologue: win0 -> buf0; win1,win2 in flight; B kl0,kl1 -> slots 0,1
    if (tid < 256) {
        p00 = *(const float4*)(Fp);
        ppA = *(const float4*)(Fp + 32);
        ppB = *(const float4*)(Fp + 64);
        CONV4(p00, 0);
    }
    LOADB2(0, 0);
    LOADB2(1, 1);
    __syncthreads();

    for (int th = 0; th < 24; th += 2) {
        // ---- even T=th: A buf0, B slots 0/1; prefetch kl 2T+2,2T+3 -> 2/3
        if (th < 23) { LOADB2(2, 2 * th + 2); LOADB2(3, 2 * th + 3); }
        MBODY(0, 0, Bh0, Bl0);
        if (tid < 256 && th < 23) CONV4(ppA, 1);           // win T+1 -> buf1
        if (tid < 256 && th < 21) ppA = *(const float4*)(Fp + (th + 3) * 32);
        MBODY(0, 1, Bh1, Bl1);
        __syncthreads();
        // ---- odd T=th+1: A buf1, B slots 2/3; prefetch -> 0/1
        const int T1 = th + 1;
        if (T1 < 23) { LOADB2(0, 2 * T1 + 2); LOADB2(1, 2 * T1 + 3); }
        MBODY(1, 0, Bh2, Bl2);
        if (tid < 256 && T1 < 23) CONV4(ppB, 0);           // win T1+1 -> buf0
        if (tid < 256 && T1 < 21) ppB = *(const float4*)(Fp + (T1 + 3) * 32);
        MBODY(1, 1, Bh3, Bl3);
        __syncthreads();
    }

    // ---- row sum-of-squares (8 staging lanes per row)
    if (tid < 256) {
        ps += __shfl_xor(ps, 1); ps += __shfl_xor(ps, 2); ps += __shfl_xor(ps, 4);
        if (sc4 == 0) ss[srow] = ps;
    }

    // ---- raw scores (verified 32x32 C/D layout:
    //      col=lane&31, row=(reg&3)+8*(reg>>2)+4*(lane>>5))
    #pragma unroll
    for (int r = 0; r < 16; ++r) {
        const int rl = (r & 3) + 8 * (r >> 2) + 4 * (lane >> 5);
        raw[rl * 196 + wid * 32 + (lane & 31)] = acc1[r] + acc2[r] * INV_LO_SCALE;
    }
    __syncthreads();

    // ---- softmax chain, one thread per row
    if (tid < 32) {
        const int r = tid;
        const float s = TAU / sqrtf(ss[r]);       // TAU / ||f||
        const float* Sr = raw + r * 196;
        float logit[9];
        #pragma unroll
        for (int d = 0; d < 9; ++d) {
            float vv[10];
            float mx = -1e30f;
            #pragma unroll
            for (int m = 0; m < 10; ++m) {
                vv[m] = s * Sr[d * 10 + m];
                mx = fmaxf(mx, vv[m]);
            }
            float den = 0.f, num = 0.f;
            #pragma unroll
            for (int m = 0; m < 10; ++m) {
                const float e = expf(vv[m] - mx);
                den += e;
                num = fmaf(e, Sr[90 + d * 10 + m], num);
            }
            logit[d] = s * num / den;             // TAU * (sep_emb . q_dom)
        }
        float mx2 = -1e30f;
        #pragma unroll
        for (int d = 0; d < 9; ++d) mx2 = fmaxf(mx2, logit[d]);
        float e2[9], den2 = 0.f;
        #pragma unroll
        for (int d = 0; d < 9; ++d) { e2[d] = expf(logit[d] - mx2); den2 += e2[d]; }
        const float inv = 1.f / den2;
        float* op = out + (row0 + r) * 9;
        #pragma unroll
        for (int d = 0; d < 9; ++d) op[d] = e2[d] * inv;
    }
}

// ---------------------------------------------------------------------------
extern "C" void kernel_launch(void* const* d_in, const int* in_sizes, int n_in,
                              void* d_out, int out_size, void* d_ws, size_t ws_size,
                              hipStream_t stream)
{
    const float* feature = (const float*)d_in[0];
    // d_in[1] = category (int64) — unused by the reference computation
    const float* Wt   = (const float*)d_in[2];
    const float* Wd   = (const float*)d_in[3];
    const float* dmem = (const float*)d_in[4];
    float* outp = (float*)d_out;
    _Float16* PBhi = (_Float16*)d_ws;                           // 294,912 B
    unsigned char* PBlo = (unsigned char*)d_ws + 192 * 768 * 2; // 147,456 B

    precompute_mw_packed<<<dim3(64, 3), 1024, 0, stream>>>(Wt, Wd, dmem, PBhi, PBlo);
    fused_memnet<<<32768 / 32, 384, 0, stream>>>(feature, PBhi, PBlo, outp);
}

// Round 14
// 66.096 us; speedup vs baseline: 1.9002x; 1.9002x over previous
//
#include <hip/hip_runtime.h>
#include <hip/hip_fp8.h>
#include <math.h>

#define TAU 32.0f
#define LO_SCALE 2048.0f
#define INV_LO_SCALE (1.0f/2048.0f)

typedef _Float16 f16x8 __attribute__((ext_vector_type(8)));
typedef _Float16 f16x4 __attribute__((ext_vector_type(4)));
typedef __fp16   fp16v2 __attribute__((ext_vector_type(2)));   // cvt_pkrtz return type
typedef float    f32x2 __attribute__((ext_vector_type(2)));
typedef float    f32x16 __attribute__((ext_vector_type(16)));

#if defined(__has_builtin)
#if __has_builtin(__builtin_amdgcn_cvt_f32_fp8) && __has_builtin(__builtin_amdgcn_cvt_pk_fp8_f32)
#define HAVE_FP8_BUILTINS 1
#endif
#if __has_builtin(__builtin_amdgcn_cvt_pk_f32_fp8) && __has_builtin(__builtin_amdgcn_cvt_pkrtz)
#define HAVE_FP8_PK 1
#endif
#endif

static __device__ __forceinline__ unsigned char enc_e4m3(float x) {
#ifdef HAVE_FP8_BUILTINS
    int p = __builtin_amdgcn_cvt_pk_fp8_f32(x, x, 0, false);
    return (unsigned char)(p & 0xff);
#else
    __hip_fp8_e4m3 q(x);
    return (unsigned char)q.__x;
#endif
}

#ifdef HAVE_FP8_BUILTINS
#define DEC_E4M3(W, SEL) __builtin_amdgcn_cvt_f32_fp8((int)(W), (SEL))
#else
static __device__ __forceinline__ float dec_e4m3_sw(unsigned w, int sel) {
    __hip_fp8_e4m3 q; q.__x = (unsigned char)((w >> (8 * sel)) & 0xff);
    return (float)q;
}
#define DEC_E4M3(W, SEL) dec_e4m3_sw((W), (SEL))
#endif

// decode 8 fp8 (e4m3) bytes -> 8 f16 (packed path halves decode VALU)
static __device__ __forceinline__ f16x8 dec8(uint2 w) {
    f16x8 r;
#ifdef HAVE_FP8_PK
    f32x2 a = __builtin_amdgcn_cvt_pk_f32_fp8((int)w.x, false);
    f32x2 b = __builtin_amdgcn_cvt_pk_f32_fp8((int)w.x, true);
    f32x2 c = __builtin_amdgcn_cvt_pk_f32_fp8((int)w.y, false);
    f32x2 d = __builtin_amdgcn_cvt_pk_f32_fp8((int)w.y, true);
    fp16v2 h0 = __builtin_amdgcn_cvt_pkrtz(a[0], a[1]);
    fp16v2 h1 = __builtin_amdgcn_cvt_pkrtz(b[0], b[1]);
    fp16v2 h2 = __builtin_amdgcn_cvt_pkrtz(c[0], c[1]);
    fp16v2 h3 = __builtin_amdgcn_cvt_pkrtz(d[0], d[1]);
    r[0] = (_Float16)h0[0]; r[1] = (_Float16)h0[1];
    r[2] = (_Float16)h1[0]; r[3] = (_Float16)h1[1];
    r[4] = (_Float16)h2[0]; r[5] = (_Float16)h2[1];
    r[6] = (_Float16)h3[0]; r[7] = (_Float16)h3[1];
#else
    r[0] = (_Float16)DEC_E4M3(w.x, 0); r[1] = (_Float16)DEC_E4M3(w.x, 1);
    r[2] = (_Float16)DEC_E4M3(w.x, 2); r[3] = (_Float16)DEC_E4M3(w.x, 3);
    r[4] = (_Float16)DEC_E4M3(w.y, 0); r[5] = (_Float16)DEC_E4M3(w.y, 1);
    r[6] = (_Float16)DEC_E4M3(w.y, 2); r[7] = (_Float16)DEC_E4M3(w.y, 3);
#endif
    return r;
}

// ---------------------------------------------------------------------------
// Kernel 1 (v4, unchanged — out of top-5 since R9): MW precompute in packed
// MFMA-fragment order; hi f16 + lo e4m3(x2048).
//   frag = (k/16)*6 + n/32 ; lane = ((k>>3)&1)*32 + (n&31), j = k&7
// ws: 192*768*2B + 192*768*1B = 442,368 B (fits proven 552,960).
// ---------------------------------------------------------------------------
__global__ __launch_bounds__(1024) void precompute_mw_packed(
    const float* __restrict__ Wt, const float* __restrict__ Wd,
    const float* __restrict__ dmem, _Float16* __restrict__ PBhi,
    unsigned char* __restrict__ PBlo)
{
    __shared__ float Ml[3 * 768];
    __shared__ float red[3][4][256];
    const int nt  = blockIdx.x;
    const int kc  = blockIdx.y;
    const int n0  = nt * 3;
    const int tid = threadIdx.x;
    const int q   = tid >> 8;
    const int kl  = tid & 255;
    const int k   = kc * 256 + kl;
    float v[3] = {0.f, 0.f, 0.f};
    if (n0 < 180) {
        const float* __restrict__ W = (n0 < 90) ? Wt : Wd;
        const int m0 = (n0 < 90) ? n0 : n0 - 90;
        for (int idx = tid; idx < 3 * 768; idx += 1024)
            Ml[idx] = dmem[m0 * 768 + idx];
        __syncthreads();
        const float* __restrict__ Wq  = W + (q * 192) * 768 + k;
        const float* __restrict__ mlb = Ml + q * 192;
        float a0 = 0.f, a1 = 0.f, a2 = 0.f;
        for (int e0 = 0; e0 < 192; e0 += 8) {
            float w[8];
            #pragma unroll
            for (int i = 0; i < 8; ++i)
                w[i] = Wq[(e0 + i) * 768];
            float4 m0a = *(const float4*)(mlb + e0);
            float4 m0b = *(const float4*)(mlb + e0 + 4);
            float4 m1a = *(const float4*)(mlb + 768 + e0);
            float4 m1b = *(const float4*)(mlb + 768 + e0 + 4);
            float4 m2a = *(const float4*)(mlb + 1536 + e0);
            float4 m2b = *(const float4*)(mlb + 1536 + e0 + 4);
            a0 = fmaf(m0a.x, w[0], a0); a0 = fmaf(m0a.y, w[1], a0);
            a0 = fmaf(m0a.z, w[2], a0); a0 = fmaf(m0a.w, w[3], a0);
            a0 = fmaf(m0b.x, w[4], a0); a0 = fmaf(m0b.y, w[5], a0);
            a0 = fmaf(m0b.z, w[6], a0); a0 = fmaf(m0b.w, w[7], a0);
            a1 = fmaf(m1a.x, w[0], a1); a1 = fmaf(m1a.y, w[1], a1);
            a1 = fmaf(m1a.z, w[2], a1); a1 = fmaf(m1a.w, w[3], a1);
            a1 = fmaf(m1b.x, w[4], a1); a1 = fmaf(m1b.y, w[5], a1);
            a1 = fmaf(m1b.z, w[6], a1); a1 = fmaf(m1b.w, w[7], a1);
            a2 = fmaf(m2a.x, w[0], a2); a2 = fmaf(m2a.y, w[1], a2);
            a2 = fmaf(m2a.z, w[2], a2); a2 = fmaf(m2a.w, w[3], a2);
            a2 = fmaf(m2b.x, w[4], a2); a2 = fmaf(m2b.y, w[5], a2);
            a2 = fmaf(m2b.z, w[6], a2); a2 = fmaf(m2b.w, w[7], a2);
        }
        red[0][q][kl] = a0;
        red[1][q][kl] = a1;
        red[2][q][kl] = a2;
        __syncthreads();
        if (q == 0) {
            #pragma unroll
            for (int i = 0; i < 3; ++i)
                v[i] = red[i][0][kl] + red[i][1][kl] + red[i][2][kl] + red[i][3][kl];
        }
    }
    if (q == 0) {
        const int t = k >> 5, ks = (k >> 4) & 1, h = (k >> 3) & 1, j = k & 7;
        const int fragc = (t * 2 + ks) * 6;
        #pragma unroll
        for (int i = 0; i < 3; ++i) {
            const int n = n0 + i;
            const int idx = (fragc + (n >> 5)) * 512 + (h * 32 + (n & 31)) * 8 + j;
            _Float16 hi = (_Float16)v[i];
            float lo = (v[i] - (float)hi) * LO_SCALE;
            PBhi[idx] = hi;
            PBlo[idx] = enc_e4m3(lo);
        }
    }
}

// ---------------------------------------------------------------------------
// Kernel 2 (v5): R12 structure with the spill removed. BM=32, 384 threads =
// 6 waves, wave wid owns col strip nt=wid. __launch_bounds__(384) ONLY —
// R12's ",6" min-waves arg forced VGPR=40 (live set ~100) -> 151 MB scratch
// spill, 175us. Natural alloc ~96-128 VGPR -> 4 waves/SIMD -> 2 blocks/CU
// = 12 waves/CU (1.5x R9), 24 barriers, 4-slot B ring, F prefetch dist 2.
// ---------------------------------------------------------------------------
#define LOADB2(S, KL) do {                                   \
    Bh##S = *(const f16x8*)(pbh + (KL) * 3072);              \
    Bl##S = *(const uint2*)(pbl + (KL) * 3072);              \
} while (0)

#define CONV4(P, BUF) do {                                   \
    float _xs[4] = {(P).x, (P).y, (P).z, (P).w};             \
    f16x4 _h, _l;                                            \
    _Pragma("unroll")                                        \
    for (int _i = 0; _i < 4; ++_i) {                         \
        float _x = _xs[_i];                                  \
        _Float16 _hh = (_Float16)_x;                         \
        _h[_i] = _hh;                                        \
        _l[_i] = (_Float16)((_x - (float)_hh) * LO_SCALE);   \
        ps += _x * _x;                                       \
    }                                                        \
    *(f16x4*)((char*)AhL[BUF] + wb) = _h;                    \
    *(f16x4*)((char*)AlL[BUF] + wb) = _l;                    \
} while (0)

#define MBODY(BUF, KS, BH, BL) do {                          \
    const int _ao = (arow * 64 + (KS) * 32 + asel) ^ swzA;   \
    f16x8 _ah = *(const f16x8*)((const char*)AhL[BUF] + _ao);\
    f16x8 _al = *(const f16x8*)((const char*)AlL[BUF] + _ao);\
    f16x8 _bl = dec8(BL);                                    \
    acc1 = __builtin_amdgcn_mfma_f32_32x32x16_f16(_ah, BH, acc1, 0, 0, 0);  \
    acc2 = __builtin_amdgcn_mfma_f32_32x32x16_f16(_ah, _bl, acc2, 0, 0, 0); \
    acc2 = __builtin_amdgcn_mfma_f32_32x32x16_f16(_al, BH, acc2, 0, 0, 0);  \
} while (0)

__global__ __launch_bounds__(384) void fused_memnet(
    const float* __restrict__ F, const _Float16* __restrict__ PBhi,
    const unsigned char* __restrict__ PBlo, float* __restrict__ out)
{
    __shared__ alignas(16) _Float16 AhL[2][32 * 32];  // 4 KB dbuf, swizzled
    __shared__ alignas(16) _Float16 AlL[2][32 * 32];  // 4 KB
    __shared__ float raw[32 * 196];                   // 25 KB epilogue
    __shared__ float ss[32];

    const int tid  = threadIdx.x;
    const int lane = tid & 63;
    const int wid  = tid / 64;        // 0..5 = col strip (nt)
    const int row0 = blockIdx.x * 32;

    // A staging ids (threads < 256 only)
    const int srow = (tid >> 3) & 31;
    const int sc4  = tid & 7;
    const float* __restrict__ Fp = F + (row0 + srow) * 768 + sc4 * 4;
    const int wb = (srow * 64 + sc4 * 8) ^ ((srow & 7) << 4);

    // packed-B per-lane bases: frag(kl, wid) at (kl*6+wid)*512 elems
    const _Float16*      __restrict__ pbh = PBhi + wid * 512 + lane * 8;
    const unsigned char* __restrict__ pbl = PBlo + wid * 512 + lane * 8;

    // A fragment read addressing
    const int arow = lane & 31;
    const int swzA = (arow & 7) << 4;
    const int asel = (lane >> 5) * 16;

    f32x16 acc1, acc2;
    #pragma unroll
    for (int r = 0; r < 16; ++r) { acc1[r] = 0.f; acc2[r] = 0.f; }

    float ps = 0.f;
    float4 p00, ppA, ppB;
    f16x8 Bh0, Bh1, Bh2, Bh3;
    uint2 Bl0, Bl1, Bl2, Bl3;

    // prologue: win0 -> buf0; win1,win2 in flight; B kl0,kl1 -> slots 0,1
    if (tid < 256) {
        p00 = *(const float4*)(Fp);
        ppA = *(const float4*)(Fp + 32);
        ppB = *(const float4*)(Fp + 64);
        CONV4(p00, 0);
    }
    LOADB2(0, 0);
    LOADB2(1, 1);
    __syncthreads();

    for (int th = 0; th < 24; th += 2) {
        // ---- even T=th: A buf0, B slots 0/1; prefetch kl 2T+2,2T+3 -> 2/3
        if (th < 23) { LOADB2(2, 2 * th + 2); LOADB2(3, 2 * th + 3); }
        MBODY(0, 0, Bh0, Bl0);
        if (tid < 256 && th < 23) CONV4(ppA, 1);           // win T+1 -> buf1
        if (tid < 256 && th < 21) ppA = *(const float4*)(Fp + (th + 3) * 32);
        MBODY(0, 1, Bh1, Bl1);
        __syncthreads();
        // ---- odd T=th+1: A buf1, B slots 2/3; prefetch -> 0/1
        const int T1 = th + 1;
        if (T1 < 23) { LOADB2(0, 2 * T1 + 2); LOADB2(1, 2 * T1 + 3); }
        MBODY(1, 0, Bh2, Bl2);
        if (tid < 256 && T1 < 23) CONV4(ppB, 0);           // win T1+1 -> buf0
        if (tid < 256 && T1 < 21) ppB = *(const float4*)(Fp + (T1 + 3) * 32);
        MBODY(1, 1, Bh3, Bl3);
        __syncthreads();
    }

    // ---- row sum-of-squares (8 staging lanes per row)
    if (tid < 256) {
        ps += __shfl_xor(ps, 1); ps += __shfl_xor(ps, 2); ps += __shfl_xor(ps, 4);
        if (sc4 == 0) ss[srow] = ps;
    }

    // ---- raw scores (verified 32x32 C/D layout:
    //      col=lane&31, row=(reg&3)+8*(reg>>2)+4*(lane>>5))
    #pragma unroll
    for (int r = 0; r < 16; ++r) {
        const int rl = (r & 3) + 8 * (r >> 2) + 4 * (lane >> 5);
        raw[rl * 196 + wid * 32 + (lane & 31)] = acc1[r] + acc2[r] * INV_LO_SCALE;
    }
    __syncthreads();

    // ---- softmax chain, one thread per row
    if (tid < 32) {
        const int r = tid;
        const float s = TAU / sqrtf(ss[r]);       // TAU / ||f||
        const float* Sr = raw + r * 196;
        float logit[9];
        #pragma unroll
        for (int d = 0; d < 9; ++d) {
            float vv[10];
            float mx = -1e30f;
            #pragma unroll
            for (int m = 0; m < 10; ++m) {
                vv[m] = s * Sr[d * 10 + m];
                mx = fmaxf(mx, vv[m]);
            }
            float den = 0.f, num = 0.f;
            #pragma unroll
            for (int m = 0; m < 10; ++m) {
                const float e = expf(vv[m] - mx);
                den += e;
                num = fmaf(e, Sr[90 + d * 10 + m], num);
            }
            logit[d] = s * num / den;             // TAU * (sep_emb . q_dom)
        }
        float mx2 = -1e30f;
        #pragma unroll
        for (int d = 0; d < 9; ++d) mx2 = fmaxf(mx2, logit[d]);
        float e2[9], den2 = 0.f;
        #pragma unroll
        for (int d = 0; d < 9; ++d) { e2[d] = expf(logit[d] - mx2); den2 += e2[d]; }
        const float inv = 1.f / den2;
        float* op = out + (row0 + r) * 9;
        #pragma unroll
        for (int d = 0; d < 9; ++d) op[d] = e2[d] * inv;
    }
}

// ---------------------------------------------------------------------------
extern "C" void kernel_launch(void* const* d_in, const int* in_sizes, int n_in,
                              void* d_out, int out_size, void* d_ws, size_t ws_size,
                              hipStream_t stream)
{
    const float* feature = (const float*)d_in[0];
    // d_in[1] = category (int64) — unused by the reference computation
    const float* Wt   = (const float*)d_in[2];
    const float* Wd   = (const float*)d_in[3];
    const float* dmem = (const float*)d_in[4];
    float* outp = (float*)d_out;
    _Float16* PBhi = (_Float16*)d_ws;                           // 294,912 B
    unsigned char* PBlo = (unsigned char*)d_ws + 192 * 768 * 2; // 147,456 B

    precompute_mw_packed<<<dim3(64, 3), 1024, 0, stream>>>(Wt, Wd, dmem, PBhi, PBlo);
    fused_memnet<<<32768 / 32, 384, 0, stream>>>(feature, PBhi, PBlo, outp);
}